// Round 8
// baseline (167.126 us; speedup 1.0000x reference)
//
#include <hip/hip_runtime.h>

// Problem: B=8, L=1024, C=384, H=6, D=64, K=2(radial), N=4(angular)
// R8: MFMA GEMMs (verified) + full-MFMA attention (R7 math verbatim) with
//     8-wave blocks (2-way in-block key split + merge) and XCD-aware swizzle.
typedef unsigned int  u32;
typedef unsigned short u16;
typedef __attribute__((ext_vector_type(8))) short short8;   // 8 bf16
typedef __attribute__((ext_vector_type(4))) float f32x4;

__device__ __forceinline__ u16 f2bf(float x) {
  union { float f; u32 u; } un; un.f = x;
  u32 r = un.u + 0x7FFFu + ((un.u >> 16) & 1u);   // RNE
  return (u16)(r >> 16);
}
__device__ __forceinline__ f32x4 mfma_bf16(short8 a, short8 b, f32x4 c) {
  return __builtin_amdgcn_mfma_f32_16x16x32_bf16(a, b, c, 0, 0, 0);
}

// ---------------- prep: RMSNorm -> xn(bf16), convert w_in/w_out -> bf16 ----
__global__ __launch_bounds__(256) void prep_kernel(
    const float* __restrict__ x, const float* __restrict__ w_norm,
    const float* __restrict__ w_in, const float* __restrict__ w_out,
    u16* __restrict__ xn, u16* __restrict__ winb, u16* __restrict__ woutb)
{
  int blk = blockIdx.x, t = threadIdx.x;
  if (blk < 2048) {               // 8192 rows, 4 rows/block (1 per wave)
    int wv = t >> 6, lane = t & 63;
    int row = blk * 4 + wv;
    const float* xr = x + (size_t)row * 384;
    float v[6]; float ss = 0.f;
    #pragma unroll
    for (int i = 0; i < 6; i++) { v[i] = xr[lane + 64 * i]; ss += v[i] * v[i]; }
    #pragma unroll
    for (int off = 32; off > 0; off >>= 1) ss += __shfl_xor(ss, off);
    float rs = __builtin_amdgcn_rsqf(ss * (1.0f / 384.0f) + 1e-5f);
    #pragma unroll
    for (int i = 0; i < 6; i++) {
      float xv = v[i] * rs * w_norm[lane + 64 * i];
      xn[(size_t)row * 384 + lane + 64 * i] = f2bf(xv);
    }
  } else {                        // weight conversion: 442368 + 147456
    int base = (blk - 2048) * 2048 + t * 8;
    #pragma unroll
    for (int j = 0; j < 8; j++) {
      int idx = base + j;
      if (idx < 442368) winb[idx] = f2bf(w_in[idx]);
      else              woutb[idx - 442368] = f2bf(w_out[idx - 442368]);
    }
  }
}

// ---------------- MFMA GEMM: out[M,.] = A[M,K](lda)*Bw[N,K](ldb)^T + bias --
// 128x128 tile, BK=64, 4 waves (2x2), 16x16x32 bf16 MFMA, padded LDS. VERIFIED.
template<bool OUT_F32, bool QSCALE>
__global__ __launch_bounds__(256) void gemm_kernel(
    const u16* __restrict__ A, int lda,
    const u16* __restrict__ Bw, int ldb,
    const float* __restrict__ bias, void* __restrict__ outp, int ldc, int K)
{
  __shared__ __attribute__((aligned(16))) u16 As[128 * 72];
  __shared__ __attribute__((aligned(16))) u16 Bs[128 * 72];
  int t = threadIdx.x;
  int lane = t & 63, wv = t >> 6;
  int g = lane >> 4, cl = lane & 15;
  int row0 = blockIdx.x * 128, col0 = blockIdx.y * 128;
  int wm = (wv >> 1) * 64, wn = (wv & 1) * 64;
  f32x4 acc[4][4];
  #pragma unroll
  for (int i = 0; i < 4; i++)
    #pragma unroll
    for (int j = 0; j < 4; j++) acc[i][j] = (f32x4){0.f, 0.f, 0.f, 0.f};

  for (int k0 = 0; k0 < K; k0 += 64) {
    __syncthreads();
    #pragma unroll
    for (int j = 0; j < 4; j++) {
      int i = t + 256 * j;
      int r = i >> 3, ch = i & 7;
      *(uint4*)(&As[r * 72 + ch * 8]) =
          *(const uint4*)(A + (size_t)(row0 + r) * lda + k0 + ch * 8);
      *(uint4*)(&Bs[r * 72 + ch * 8]) =
          *(const uint4*)(Bw + (size_t)(col0 + r) * ldb + k0 + ch * 8);
    }
    __syncthreads();
    #pragma unroll
    for (int kh = 0; kh < 2; kh++) {
      short8 af[4], bfr[4];
      #pragma unroll
      for (int s = 0; s < 4; s++) {
        af[s]  = *(const short8*)(&As[(wm + s * 16 + cl) * 72 + kh * 32 + g * 8]);
        bfr[s] = *(const short8*)(&Bs[(wn + s * 16 + cl) * 72 + kh * 32 + g * 8]);
      }
      #pragma unroll
      for (int i = 0; i < 4; i++)
        #pragma unroll
        for (int j = 0; j < 4; j++)
          acc[i][j] = mfma_bf16(af[i], bfr[j], acc[i][j]);
    }
  }
  // epilogue: C/D layout col=lane&15, row=4*(lane>>4)+r  [HW-verified R4]
  #pragma unroll
  for (int i = 0; i < 4; i++) {
    #pragma unroll
    for (int j = 0; j < 4; j++) {
      int colb = col0 + wn + j * 16 + cl;
      float bv = bias[colb];
      #pragma unroll
      for (int r = 0; r < 4; r++) {
        int rowb = row0 + wm + i * 16 + g * 4 + r;
        float v = acc[i][j][r] + bv;
        if (QSCALE) { if (colb < 384) v *= 0.125f; }   // fold 1/sqrt(D) into Q
        if (OUT_F32) ((float*)outp)[(size_t)rowb * ldc + colb] = v;
        else ((u16*)outp)[(size_t)rowb * ldc + colb] = f2bf(v);
      }
    }
  }
}

// ---------------- full-MFMA attention, 8 waves, 2-way key split ------------
// Block = (b, h, 64 q-rows); wave (strip = wv&3, half = wv>>2): q-rows
// strip*16..+15, keys [half*512, half*512+512). Per 64-key tile (R7 verbatim):
//   V-stage -> vsmem[half], QK^T MFMA + polar bias -> sbuf[half],
//   per-wave softmax + in-register P A-frags + PV MFMA.
// End: halves merged via LDS (R5-verified online-softmax combine).
__global__ __launch_bounds__(512) void attn_hybrid4(
    const u16* __restrict__ qkv, const float* __restrict__ pos,
    const float* __restrict__ bcf, const float* __restrict__ ccf,
    u16* __restrict__ obuf)
{
  __shared__ __attribute__((aligned(16))) float sbuf[2][64][66];  // 33792 B
  __shared__ __attribute__((aligned(16))) u16 vsmem[2][64][72];   // 18432 B
  __shared__ float mlbuf[2][4][16];                               //   512 B

  // XCD-aware remap: all 16 q-tiles of one (b,h) share bid%8 -> same XCD L2.
  int bid = blockIdx.x;
  int xslot = bid & 7, rest = bid >> 3;       // 768 = 8 * 96
  int qt = rest & 15, gdiv = rest >> 4;       // gdiv in [0,6)
  int g48 = gdiv * 8 + xslot;                 // (b*6 + h) in [0,48)
  int b = g48 / 6, h = g48 - b * 6;

  int t = threadIdx.x, lane = t & 63, wv = t >> 6;   // 8 waves
  int strip = wv & 3, half = wv >> 2;
  int g = lane >> 4, cl = lane & 15;

  float bc[15], cc[15];
  #pragma unroll
  for (int i = 0; i < 15; i++) { bc[i] = bcf[h * 15 + i]; cc[i] = ccf[h * 15 + i]; }

  // Q fragments (A-operand): rows strip*16+cl; Q pre-scaled by 1/8 in GEMM1
  const u16* qbase =
      qkv + (size_t)(b * 1024 + qt * 64 + strip * 16 + cl) * 1152 + h * 64;
  short8 qf0 = *(const short8*)(qbase + g * 8);
  short8 qf1 = *(const short8*)(qbase + 32 + g * 8);

  // bias q positions for this lane's S rows (4g+r within wave strip)
  float qx[4], qy[4];
  #pragma unroll
  for (int r = 0; r < 4; r++) {
    int qr = qt * 64 + strip * 16 + 4 * g + r;
    qx[r] = pos[(size_t)(b * 1024 + qr) * 2 + 0];
    qy[r] = pos[(size_t)(b * 1024 + qr) * 2 + 1];
  }

  f32x4 oa[4];
  #pragma unroll
  for (int d = 0; d < 4; d++) oa[d] = (f32x4){0.f, 0.f, 0.f, 0.f};
  float m_own = -1e30f, l_own = 0.f;   // softmax state: lane owns row cl

  const u16* kb = qkv + (size_t)b * 1024 * 1152 + 384 + h * 64;
  const u16* vsrc = qkv + (size_t)b * 1024 * 1152 + 768 + h * 64 + strip * 16;
  const float* pb = pos + (size_t)b * 2048;

  for (int kt = 0; kt < 512; kt += 64) {
    int k0 = half * 512 + kt;
    // ---- V-stage: vsmem[half][dim][key], wave handles dims strip*16..+15 ----
    {
      const u16* vr = vsrc + (size_t)(k0 + lane) * 1152;
      uint4 w0 = *(const uint4*)(vr);
      uint4 w1 = *(const uint4*)(vr + 8);
      int vd = strip * 16;
      vsmem[half][vd + 0][lane] = (u16)(w0.x);  vsmem[half][vd + 1][lane] = (u16)(w0.x >> 16);
      vsmem[half][vd + 2][lane] = (u16)(w0.y);  vsmem[half][vd + 3][lane] = (u16)(w0.y >> 16);
      vsmem[half][vd + 4][lane] = (u16)(w0.z);  vsmem[half][vd + 5][lane] = (u16)(w0.z >> 16);
      vsmem[half][vd + 6][lane] = (u16)(w0.w);  vsmem[half][vd + 7][lane] = (u16)(w0.w >> 16);
      vsmem[half][vd + 8][lane] = (u16)(w1.x);  vsmem[half][vd + 9][lane] = (u16)(w1.x >> 16);
      vsmem[half][vd +10][lane] = (u16)(w1.y);  vsmem[half][vd +11][lane] = (u16)(w1.y >> 16);
      vsmem[half][vd +12][lane] = (u16)(w1.z);  vsmem[half][vd +13][lane] = (u16)(w1.z >> 16);
      vsmem[half][vd +14][lane] = (u16)(w1.w);  vsmem[half][vd +15][lane] = (u16)(w1.w >> 16);
    }
    // ---- phase 1 (verified): S = (Q/8)K^T + bias -> sbuf[half] ----
    f32x4 s[4];
    #pragma unroll
    for (int ks = 0; ks < 4; ks++) {
      const u16* kr = kb + (size_t)(k0 + ks * 16 + cl) * 1152;
      short8 kf0 = *(const short8*)(kr + g * 8);
      short8 kf1 = *(const short8*)(kr + 32 + g * 8);
      f32x4 z = (f32x4){0.f, 0.f, 0.f, 0.f};
      z = mfma_bf16(qf0, kf0, z);
      z = mfma_bf16(qf1, kf1, z);
      s[ks] = z;
    }
    #pragma unroll
    for (int ks = 0; ks < 4; ks++) {
      int kidx = k0 + ks * 16 + cl;
      float kx = pb[kidx * 2], ky = pb[kidx * 2 + 1];
      #pragma unroll
      for (int r = 0; r < 4; r++) {
        float dx = qx[r] - kx, dy = qy[r] - ky;
        float r2 = dx * dx + dy * dy;
        bool zz = !(r2 > 0.f);
        float ir = zz ? 0.f : __builtin_amdgcn_rsqf(r2);
        float rr = r2 * ir;
        float c1 = zz ? 1.f : dx * ir;
        float s1 = dy * ir;
        float c2 = c1*c1 - s1*s1, s2 = 2.f*c1*s1;
        float c3 = c1*c2 - s1*s2, s3 = s1*c2 + c1*s2;
        float c4 = c2*c2 - s2*s2, s4 = 2.f*c2*s2;
        float a0 = bc[0] + bc[1]*c1 + bc[2]*c2 + bc[3]*c3 + bc[4]*c4
                 + cc[1]*s1 + cc[2]*s2 + cc[3]*s3 + cc[4]*s4;
        float a1 = bc[5] + bc[6]*c1 + bc[7]*c2 + bc[8]*c3 + bc[9]*c4
                 + cc[6]*s1 + cc[7]*s2 + cc[8]*s3 + cc[9]*s4;
        float a2 = bc[10] + bc[11]*c1 + bc[12]*c2 + bc[13]*c3 + bc[14]*c4
                 + cc[11]*s1 + cc[12]*s2 + cc[13]*s3 + cc[14]*s4;
        sbuf[half][strip * 16 + 4 * g + r][ks * 16 + cl] =
            s[ks][r] + a0 + rr * (a1 + rr * a2);
      }
    }
    __syncthreads();                    // vsmem[half] staged by 4 waves
    // ---- phase 2: per-wave softmax + MFMA PV (R7 verbatim) ----
    {
      int rown = strip * 16 + cl, cb = g * 16;
      float tmax = -1e30f;
      #pragma unroll
      for (int c = 0; c < 16; c++) tmax = fmaxf(tmax, sbuf[half][rown][cb + c]);
      tmax = fmaxf(tmax, __shfl_xor(tmax, 16));
      tmax = fmaxf(tmax, __shfl_xor(tmax, 32));
      float mn = fmaxf(m_own, tmax);
      float sc = __builtin_amdgcn_exp2f((m_own - mn) * 1.44269504f);
      m_own = mn;
      #pragma unroll
      for (int r = 0; r < 4; r++) {
        float scr = __shfl(sc, 4 * g + r);
        #pragma unroll
        for (int d = 0; d < 4; d++) oa[d][r] *= scr;
      }
      float psum = 0.f;
      union { u16 u[8]; short8 s8; } pk0, pk1;
      const float* srow = &sbuf[half][strip * 16 + cl][0];
      #pragma unroll
      for (int j = 0; j < 8; j++) {
        float p = __builtin_amdgcn_exp2f((srow[8 * g + j] - mn) * 1.44269504f);
        psum += p; pk0.u[j] = f2bf(p);
      }
      #pragma unroll
      for (int j = 0; j < 8; j++) {
        float p = __builtin_amdgcn_exp2f((srow[32 + 8 * g + j] - mn) * 1.44269504f);
        psum += p; pk1.u[j] = f2bf(p);
      }
      psum += __shfl_xor(psum, 16);
      psum += __shfl_xor(psum, 32);
      l_own = l_own * sc + psum;
      #pragma unroll
      for (int d = 0; d < 4; d++) {
        short8 vf0 = *(const short8*)(&vsmem[half][d * 16 + cl][g * 8]);
        short8 vf1 = *(const short8*)(&vsmem[half][d * 16 + cl][32 + g * 8]);
        oa[d] = mfma_bf16(pk0.s8, vf0, oa[d]);
        oa[d] = mfma_bf16(pk1.s8, vf1, oa[d]);
      }
    }
    __syncthreads();                    // sbuf/vsmem reused next tile
  }
  // ---- merge the two key-halves (R5-verified combine), overlay sbuf ----
  float* o1 = &sbuf[0][0][0];           // [4][16][64] f32 = 16 KB
  if (half == 1) {
    if (lane < 16) { mlbuf[0][strip][lane] = m_own; mlbuf[1][strip][lane] = l_own; }
    #pragma unroll
    for (int r = 0; r < 4; r++) {
      int row = 4 * g + r;
      #pragma unroll
      for (int d = 0; d < 4; d++)
        o1[(strip * 16 + row) * 64 + d * 16 + cl] = oa[d][r];
    }
  }
  __syncthreads();
  if (half == 0) {
    float m1 = mlbuf[0][strip][cl], l1 = mlbuf[1][strip][cl];
    float M  = fmaxf(m_own, m1);
    float f0 = __builtin_amdgcn_exp2f((m_own - M) * 1.44269504f);
    float f1 = __builtin_amdgcn_exp2f((m1    - M) * 1.44269504f);
    float linv = __builtin_amdgcn_rcpf(l_own * f0 + l1 * f1);
    #pragma unroll
    for (int r = 0; r < 4; r++) {
      int row = 4 * g + r;
      float f0r = __shfl(f0, row), f1r = __shfl(f1, row), invr = __shfl(linv, row);
      int qr = qt * 64 + strip * 16 + row;
      #pragma unroll
      for (int d = 0; d < 4; d++) {
        float val = (oa[d][r] * f0r +
                     o1[(strip * 16 + row) * 64 + d * 16 + cl] * f1r) * invr;
        obuf[(size_t)(b * 1024 + qr) * 384 + h * 64 + d * 16 + cl] = f2bf(val);
      }
    }
  }
}

// ---------------- launch ---------------------------------------------------
extern "C" void kernel_launch(void* const* d_in, const int* in_sizes, int n_in,
                              void* d_out, int out_size, void* d_ws, size_t ws_size,
                              hipStream_t stream) {
  const float* x      = (const float*)d_in[0];
  const float* pos    = (const float*)d_in[1];
  const float* w_norm = (const float*)d_in[2];
  const float* w_in   = (const float*)d_in[3];
  const float* b_in   = (const float*)d_in[4];
  const float* w_out  = (const float*)d_in[5];
  const float* b_out  = (const float*)d_in[6];
  const float* b_coef = (const float*)d_in[7];
  const float* c_coef = (const float*)d_in[8];

  char* ws = (char*)d_ws;
  // ws layout (25.1 MB):
  //   [0, 6291456)        xn (bf16 8192x384); obuf overlays it (xn dead after GEMM1)
  //   [6291456, 7176192)  winb (bf16 1152x384)
  //   [7176192, 7471104)  woutb (bf16 384x384)
  //   [7471104, 26345472) qkv (bf16 8192x1152), Q pre-scaled by 1/8
  u16* xn    = (u16*)(ws + 0);
  u16* obuf  = (u16*)(ws + 0);          // overlays xn
  u16* winb  = (u16*)(ws + 6291456);
  u16* woutb = (u16*)(ws + 7176192);
  u16* qkvb  = (u16*)(ws + 7471104);

  prep_kernel<<<2336, 256, 0, stream>>>(x, w_norm, w_in, w_out, xn, winb, woutb);
  gemm_kernel<false, true><<<dim3(64, 9), 256, 0, stream>>>(
      xn, 384, winb, 384, b_in, qkvb, 1152, 384);
  attn_hybrid4<<<768, 512, 0, stream>>>(qkvb, pos, b_coef, c_coef, obuf);
  gemm_kernel<true, false><<<dim3(64, 3), 256, 0, stream>>>(
      obuf, 384, woutb, 384, b_out, (float*)d_out, 384, 384);
}